// Round 17
// baseline (4664.542 us; speedup 1.0000x reference)
//
#include <hip/hip_runtime.h>
#include <stdint.h>

// ---------------------------------------------------------------------------
// GRU encoder (B=128,T=512,D=512,H=512,L=256), MI355X gfx950.
//
// R21: NO-IG design. ig_gemm (250us serial + 201MB write + 201MB read) is
// deleted; each ring wave computes its x_t @ Wih^T slice IN the recurrence,
// in the dead time between publishing flag(t) and polling for h_t (the
// x-part has no h dependency). Wih slice (3x32colsxK=512 bf16 = 96KB) is
// staged once into LDS with R17's proven zero-bank-conflict fragment
// layout; Whh stays in registers (R14-proven 192 VGPR block).
// Step: [x-loads+pack+48 x-MFMAs] -> R14-exact serial poll (dev scope +
// sys escalation; R20 proved aggressive polling CONGESTS the fabric and
// doubles time -> reverted) -> load_h16 -> 48 h-MFMAs -> gates -> store ->
// drain -> flag. Ring protocol byte-identical to R14 (best of 17 variants,
// gru_rec 1998us).
// Gate algebra (USE_IG=false path, verified vs reference): ar/az/ai carry
// x@Wih_{r,z,n}; xr=ar+b_r, xz=az+b_z, xin=ai+b_n, n=tanh(xin+r*(an+bn)).
// Workspace: hbuf + flags + hfin only (~525KB); no 203MB IG buffer.
// ---------------------------------------------------------------------------

typedef short short8 __attribute__((ext_vector_type(8)));
typedef float f32x4 __attribute__((ext_vector_type(4)));
typedef int int4v __attribute__((ext_vector_type(4)));

#define NB 128
#define NT 512
#define ND 512
#define NH 512

__device__ __forceinline__ unsigned short f2bf(float f) {
  union { float f; unsigned u; } v; v.f = f;
  unsigned r = v.u + 0x7fffu + ((v.u >> 16) & 1u);  // RNE
  return (unsigned short)(r >> 16);
}
__device__ __forceinline__ float sigmoid_f(float x) {
  float e = __builtin_amdgcn_exp2f(-1.4426950408889634f * x);
  return __builtin_amdgcn_rcpf(1.0f + e);
}
__device__ __forceinline__ float tanh_f(float x) {
  float e = __builtin_amdgcn_exp2f(2.8853900817779268f * x);
  return 1.0f - 2.0f * __builtin_amdgcn_rcpf(1.0f + e);
}
__device__ __forceinline__ short8 pack8(float4 a, float4 b) {
  short8 s;
  s[0] = (short)f2bf(a.x); s[1] = (short)f2bf(a.y);
  s[2] = (short)f2bf(a.z); s[3] = (short)f2bf(a.w);
  s[4] = (short)f2bf(b.x); s[5] = (short)f2bf(b.y);
  s[6] = (short)f2bf(b.z); s[7] = (short)f2bf(b.w);
  return s;
}

// 16 device-scope 16B loads (this lane's h A-fragments for K=512) + drain.
__device__ __forceinline__ void load_h16(const unsigned short* p, int4v a[16]) {
  asm volatile(
      "global_load_dwordx4 %0,  %16, off sc1\n\t"
      "global_load_dwordx4 %1,  %16, off offset:64 sc1\n\t"
      "global_load_dwordx4 %2,  %16, off offset:128 sc1\n\t"
      "global_load_dwordx4 %3,  %16, off offset:192 sc1\n\t"
      "global_load_dwordx4 %4,  %16, off offset:256 sc1\n\t"
      "global_load_dwordx4 %5,  %16, off offset:320 sc1\n\t"
      "global_load_dwordx4 %6,  %16, off offset:384 sc1\n\t"
      "global_load_dwordx4 %7,  %16, off offset:448 sc1\n\t"
      "global_load_dwordx4 %8,  %16, off offset:512 sc1\n\t"
      "global_load_dwordx4 %9,  %16, off offset:576 sc1\n\t"
      "global_load_dwordx4 %10, %16, off offset:640 sc1\n\t"
      "global_load_dwordx4 %11, %16, off offset:704 sc1\n\t"
      "global_load_dwordx4 %12, %16, off offset:768 sc1\n\t"
      "global_load_dwordx4 %13, %16, off offset:832 sc1\n\t"
      "global_load_dwordx4 %14, %16, off offset:896 sc1\n\t"
      "global_load_dwordx4 %15, %16, off offset:960 sc1\n\t"
      "s_waitcnt vmcnt(0)"
      : "=&v"(a[0]), "=&v"(a[1]), "=&v"(a[2]), "=&v"(a[3]),
        "=&v"(a[4]), "=&v"(a[5]), "=&v"(a[6]), "=&v"(a[7]),
        "=&v"(a[8]), "=&v"(a[9]), "=&v"(a[10]), "=&v"(a[11]),
        "=&v"(a[12]), "=&v"(a[13]), "=&v"(a[14]), "=&v"(a[15])
      : "v"(p)
      : "memory");
}

// 4 device-scope short stores (rows erow..erow+3, stride NH*2=1024B) + drain
// so the subsequent flag store implies device-wide visibility of this slice.
__device__ __forceinline__ void store_h4(unsigned short* p, unsigned v0,
                                         unsigned v1, unsigned v2, unsigned v3) {
  asm volatile(
      "global_store_short %0, %1, off sc1\n\t"
      "global_store_short %0, %2, off offset:1024 sc1\n\t"
      "global_store_short %0, %3, off offset:2048 sc1\n\t"
      "global_store_short %0, %4, off offset:3072 sc1\n\t"
      "s_waitcnt vmcnt(0)"
      :
      : "v"(p), "v"(v0), "v"(v1), "v"(v2), "v"(v3)
      : "memory");
}

__device__ __forceinline__ unsigned poll_load_dev(const unsigned* p) {
  unsigned f;
  asm volatile(
      "global_load_dword %0, %1, off sc1\n\t"
      "s_waitcnt vmcnt(0)"
      : "=v"(f) : "v"(p) : "memory");
  return f;
}
__device__ __forceinline__ unsigned poll_load_sys(const unsigned* p) {
  unsigned f;
  asm volatile(
      "global_load_dword %0, %1, off sc0 sc1\n\t"
      "s_waitcnt vmcnt(0)"
      : "=v"(f) : "v"(p) : "memory");
  return f;
}
__device__ __forceinline__ void flag_store(unsigned* p, unsigned v) {
  asm volatile("global_store_dword %0, %1, off sc1"
               :: "v"(p), "v"(v) : "memory");
}

// ---------------------------------------------------------------------------
// Persistent GRU recurrence. 64 blocks x 256 threads. (R14 topology/protocol)
// block = (group g of 32 batch rows, chunk c of 32 h-cols).
// wave (wm,wn): rows [b0+wm*16, +16), cols [c*32+wn*16, +16).
// Whh fragments in REGISTERS (bfr, 192 VGPR); Wih fragments in LDS
// (Wlds[((gate*16+kk)*4+q)*32+ci], R17-proven zero-conflict layout).
// flags[((g*2+wm)*16+c)*2+wn] = step count (h stores drained before flag).
// ---------------------------------------------------------------------------
__global__ __launch_bounds__(256, 1) void gru_rec(
    const float* __restrict__ x, const float* __restrict__ Wih,
    const float* __restrict__ Whh, const float* __restrict__ bias,
    const float* __restrict__ bn, unsigned short* __restrict__ hbuf,
    unsigned* __restrict__ flags, float* __restrict__ hfin) {
  __shared__ short8 Wlds[3 * 16 * 4 * 32];  // 96 KB Wih bf16 fragments

  const int tid = threadIdx.x;
  const int lane = tid & 63;
  const int w = tid >> 6;
  const int wm = w >> 1, wn = w & 1;
  const int l15 = lane & 15, q = lane >> 4;
  const int g = blockIdx.x >> 4;   // 4 groups
  const int c = blockIdx.x & 15;   // 16 col-chunks of 32
  const int b0 = g * 32;
  const int col = c * 32 + wn * 16 + l15;  // this lane's h column
  const int mrow = b0 + wm * 16 + l15;     // A-fragment batch row
  const int erow = b0 + wm * 16 + q * 4;   // C-layout batch row base
  const int ci = wn * 16 + l15;            // Wlds col index

  unsigned* const myflag = flags + ((g * 2 + wm) * 16 + c) * 2 + wn;
  const unsigned* const pollbase = flags + (g * 2 + wm) * 32;  // 32 flags

  // Stage Wih fragments -> LDS (R17 staging pattern, zero bank conflicts).
#pragma unroll
  for (int j = 0; j < 24; ++j) {
    int fid = tid + 256 * j;
    int gate = fid >> 11;
    int rem = fid & 2047;
    int kk = rem >> 7;
    int q2 = (rem >> 5) & 3;
    int colIdx = rem & 31;
    const float* src = Wih + (size_t)(gate * NH + c * 32 + colIdx) * ND + kk * 32 + q2 * 8;
    Wlds[((gate * 16 + kk) * 4 + q2) * 32 + colIdx] =
        pack8(*(const float4*)src, *(const float4*)(src + 4));
  }

  // Whh B-fragments -> registers: 3 gates x 16 k-chunks (192 VGPRs)
  short8 bfr[3][16];
#pragma unroll
  for (int gt = 0; gt < 3; ++gt) {
    const float* src = Whh + (size_t)(gt * NH + col) * NH + q * 8;
#pragma unroll
    for (int kk = 0; kk < 16; ++kk) {
      float4 v0 = *(const float4*)(src + kk * 32);
      float4 v1 = *(const float4*)(src + kk * 32 + 4);
      bfr[gt][kk] = pack8(v0, v1);
    }
  }
  __syncthreads();  // Wlds ready

  const float bi_r = bias[col];
  const float bi_z = bias[NH + col];
  const float bi_n = bias[2 * NH + col];
  const float bnv = bn[col];

  float hreg[4] = {0.f, 0.f, 0.f, 0.f};

  unsigned short* const hb0 = hbuf;
  unsigned short* const hb1 = hbuf + NB * NH;

  for (int t = 0; t < NT; ++t) {
    const unsigned short* hcur = (t & 1) ? hb1 : hb0;
    unsigned short* hnxt = (t & 1) ? hb0 : hb1;

    // ---- x-part: x_t @ Wih^T for this wave's slice. NO h dependency —
    // executes between flag(t) publish (end of last iter) and the poll,
    // filling the ring's dead wait time (replaces the old IG loads).
    f32x4 ar = {0.f, 0.f, 0.f, 0.f};
    f32x4 az = {0.f, 0.f, 0.f, 0.f};
    f32x4 an = {0.f, 0.f, 0.f, 0.f};
    f32x4 ai = {0.f, 0.f, 0.f, 0.f};
#pragma unroll
    for (int kk = 0; kk < 16; ++kk) {
      const float* xp = x + ((size_t)mrow * NT + t) * ND + kk * 32 + q * 8;
      short8 xa = pack8(*(const float4*)xp, *(const float4*)(xp + 4));
      const short8 wr = Wlds[((0 * 16 + kk) * 4 + q) * 32 + ci];
      const short8 wz = Wlds[((1 * 16 + kk) * 4 + q) * 32 + ci];
      const short8 wn8 = Wlds[((2 * 16 + kk) * 4 + q) * 32 + ci];
      ar = __builtin_amdgcn_mfma_f32_16x16x32_bf16(xa, wr, ar, 0, 0, 0);
      az = __builtin_amdgcn_mfma_f32_16x16x32_bf16(xa, wz, az, 0, 0, 0);
      ai = __builtin_amdgcn_mfma_f32_16x16x32_bf16(xa, wn8, ai, 0, 0, 0);
    }

    // ---- h-part: R14-exact poll -> load -> MFMA
    int4v araw[16];
    if (t > 0) {
      if (lane < 32) {
        const unsigned* fp = pollbase + lane;
        unsigned f = poll_load_dev(fp);
        int tries = 0;
        while ((int)f < t) {
          if (++tries > 8) f = poll_load_sys(fp);
          else             f = poll_load_dev(fp);
        }
      }
      // implicit reconvergence: all lanes proceed after slowest poll
      load_h16(hcur + (size_t)mrow * NH + q * 8, araw);
#pragma unroll
      for (int kk = 0; kk < 16; ++kk) {
        short8 afk = __builtin_bit_cast(short8, araw[kk]);
        ar = __builtin_amdgcn_mfma_f32_16x16x32_bf16(afk, bfr[0][kk], ar, 0, 0, 0);
        az = __builtin_amdgcn_mfma_f32_16x16x32_bf16(afk, bfr[1][kk], az, 0, 0, 0);
        an = __builtin_amdgcn_mfma_f32_16x16x32_bf16(afk, bfr[2][kk], an, 0, 0, 0);
      }
    }
    // t == 0: h_0 = 0 -> h-part contributes nothing (an stays 0).

    // ---- gates + h update; store via device-scope stores, drain, flag
    unsigned sv[4];
#pragma unroll
    for (int i = 0; i < 4; ++i) {
      float xr = ar[i] + bi_r;
      float xz = az[i] + bi_z;
      float xin = ai[i] + bi_n;
      float r = sigmoid_f(xr);
      float z = sigmoid_f(xz);
      float n = tanh_f(xin + r * (an[i] + bnv));
      float hn2 = (1.f - z) * n + z * hreg[i];
      hreg[i] = hn2;
      sv[i] = (unsigned)f2bf(hn2);
      if (t == NT - 1) hfin[(size_t)(erow + i) * NH + col] = hn2;
    }
    if (t != NT - 1) {
      store_h4(hnxt + (size_t)erow * NH + col, sv[0], sv[1], sv[2], sv[3]);
      if (lane == 0) flag_store(myflag, (unsigned)(t + 1));
    }
  }
}

// ---------------------------------------------------------------------------
// out = h_T @ Wlin^T + blin; mu = cols [0,256), logvar = cols [256,512).
// ---------------------------------------------------------------------------
__global__ __launch_bounds__(256) void final_linear(
    const float* __restrict__ hfin, const float* __restrict__ Wlin,
    const float* __restrict__ blin, float* __restrict__ out) {
  __shared__ float sh[16 * 516];
  const int tid = threadIdx.x;
  const int b0 = blockIdx.y * 16, o0 = blockIdx.x * 16;

  for (int j = tid; j < 16 * 128; j += 256) {
    int row = j >> 7, kq = j & 127;
    *(float4*)&sh[row * 516 + kq * 4] =
        *(const float4*)(hfin + (size_t)(b0 + row) * NH + kq * 4);
  }
  __syncthreads();

  const int bi = tid & 15, oi = tid >> 4;
  const int o = o0 + oi;
  const float4* wp = (const float4*)(Wlin + (size_t)o * NH);
  float4 a4 = {0.f, 0.f, 0.f, 0.f};
  for (int k4 = 0; k4 < 128; ++k4) {
    float4 wv = wp[k4];
    float4 hv = *(const float4*)&sh[bi * 516 + k4 * 4];
    a4.x += wv.x * hv.x; a4.y += wv.y * hv.y;
    a4.z += wv.z * hv.z; a4.w += wv.w * hv.w;
  }
  float v = a4.x + a4.y + a4.z + a4.w + blin[o];
  int b = b0 + bi;
  if (o < 256) out[b * 256 + o] = v;
  else out[32768 + b * 256 + (o - 256)] = v;
}

// ---------------------------------------------------------------------------
extern "C" void kernel_launch(void* const* d_in, const int* in_sizes, int n_in,
                              void* d_out, int out_size, void* d_ws, size_t ws_size,
                              hipStream_t stream) {
  const float* x    = (const float*)d_in[0];
  const float* Wih  = (const float*)d_in[1];
  const float* Whh  = (const float*)d_in[2];
  const float* bias = (const float*)d_in[3];
  const float* bn   = (const float*)d_in[4];
  const float* Wlin = (const float*)d_in[5];
  const float* blin = (const float*)d_in[6];
  float* out = (float*)d_out;

  char* ws = (char*)d_ws;
  // layout: [hbuf 262144][flags 1024][hfin 262144]  (no IG buffer)
  unsigned short* hbuf = (unsigned short*)ws;
  unsigned* flags      = (unsigned*)(ws + 262144);
  float* hfin          = (float*)(ws + 263168);
  const size_t need_min = 525312;
  if (ws_size < need_min) return;

  // zero flags only (h_0 is synthesized in registers; hbuf needs no init)
  hipMemsetAsync(ws + 262144, 0, 1024, stream);

  gru_rec<<<64, 256, 0, stream>>>(x, Wih, Whh, bias, bn, hbuf, flags, hfin);
  final_linear<<<dim3(32, 8), 256, 0, stream>>>(hfin, Wlin, blin, out);
}

// Round 19
// 2266.379 us; speedup vs baseline: 2.0581x; 2.0581x over previous
//
#include <hip/hip_runtime.h>
#include <stdint.h>

// ---------------------------------------------------------------------------
// GRU encoder (B=128,T=512,D=512,H=512,L=256), MI355X gfx950.
//
// R23 = R15 RESUBMITTED (verified best: total 2252us; R22's run died before
// the bench's first message — infra flake, source identical to R15-passing).
// Fused producer-consumer launch: one 256-block kernel; blocks 0..63 =
// R14-exact recurrence ring (measured floor ~2000us across 18 protocol
// variants); blocks 64..255 = persistent IG producers (tiles quarter-major
// so early timesteps finish first). R21 proved work folded INTO the ring
// adds its full cost to the ring period (symmetric-shift fallacy) —
// producers must run on OTHER CUs, which is exactly this structure.
//   producer tile: gemm body -> sc0sc1 IG stores -> vmcnt(0) drain ->
//                  igflag[bm*12+bn]=1 (system scope).
//   consumer: at t%128==0 poll the 96 tile flags covering its group's rows
//             x 3 gate-columns BEFORE touching that quarter's IG.
// Ring: drain-then-flag producer, dev-scope poll with sys escalation,
// load_h16, 48 MFMA, gates. Whh in 192 VGPRs. h_0 synthesized (no memset).
// Measured (R15): gru_fused 2318us, FETCH 1.05GB, WRITE 266MB, MfmaUtil 3.6.
// Structural conclusion: remaining time is 512 sequential steps x ~3.9us of
// cross-XCD publish->observe->reload latency (MfmaUtil 2-4%, HBM 3-7% —
// neither pipe is the limit; the interconnect RT chain is).
// ---------------------------------------------------------------------------

typedef short short8 __attribute__((ext_vector_type(8)));
typedef float f32x4 __attribute__((ext_vector_type(4)));
typedef int int4v __attribute__((ext_vector_type(4)));

#define NB 128
#define NT 512
#define ND 512
#define NH 512
#define NG 1536  // 3H

__device__ __forceinline__ unsigned short f2bf(float f) {
  union { float f; unsigned u; } v; v.f = f;
  unsigned r = v.u + 0x7fffu + ((v.u >> 16) & 1u);  // RNE
  return (unsigned short)(r >> 16);
}
__device__ __forceinline__ float bf2f(unsigned short u) {
  union { unsigned u; float f; } v; v.u = ((unsigned)u) << 16; return v.f;
}
__device__ __forceinline__ float sigmoid_f(float x) {
  float e = __builtin_amdgcn_exp2f(-1.4426950408889634f * x);
  return __builtin_amdgcn_rcpf(1.0f + e);
}
__device__ __forceinline__ float tanh_f(float x) {
  float e = __builtin_amdgcn_exp2f(2.8853900817779268f * x);
  return 1.0f - 2.0f * __builtin_amdgcn_rcpf(1.0f + e);
}
__device__ __forceinline__ short8 pack8(float4 a, float4 b) {
  short8 s;
  s[0] = (short)f2bf(a.x); s[1] = (short)f2bf(a.y);
  s[2] = (short)f2bf(a.z); s[3] = (short)f2bf(a.w);
  s[4] = (short)f2bf(b.x); s[5] = (short)f2bf(b.y);
  s[6] = (short)f2bf(b.z); s[7] = (short)f2bf(b.w);
  return s;
}

// 16 device-scope 16B loads (this lane's A-fragments for K=512) + one drain.
__device__ __forceinline__ void load_h16(const unsigned short* p, int4v a[16]) {
  asm volatile(
      "global_load_dwordx4 %0,  %16, off sc1\n\t"
      "global_load_dwordx4 %1,  %16, off offset:64 sc1\n\t"
      "global_load_dwordx4 %2,  %16, off offset:128 sc1\n\t"
      "global_load_dwordx4 %3,  %16, off offset:192 sc1\n\t"
      "global_load_dwordx4 %4,  %16, off offset:256 sc1\n\t"
      "global_load_dwordx4 %5,  %16, off offset:320 sc1\n\t"
      "global_load_dwordx4 %6,  %16, off offset:384 sc1\n\t"
      "global_load_dwordx4 %7,  %16, off offset:448 sc1\n\t"
      "global_load_dwordx4 %8,  %16, off offset:512 sc1\n\t"
      "global_load_dwordx4 %9,  %16, off offset:576 sc1\n\t"
      "global_load_dwordx4 %10, %16, off offset:640 sc1\n\t"
      "global_load_dwordx4 %11, %16, off offset:704 sc1\n\t"
      "global_load_dwordx4 %12, %16, off offset:768 sc1\n\t"
      "global_load_dwordx4 %13, %16, off offset:832 sc1\n\t"
      "global_load_dwordx4 %14, %16, off offset:896 sc1\n\t"
      "global_load_dwordx4 %15, %16, off offset:960 sc1\n\t"
      "s_waitcnt vmcnt(0)"
      : "=&v"(a[0]), "=&v"(a[1]), "=&v"(a[2]), "=&v"(a[3]),
        "=&v"(a[4]), "=&v"(a[5]), "=&v"(a[6]), "=&v"(a[7]),
        "=&v"(a[8]), "=&v"(a[9]), "=&v"(a[10]), "=&v"(a[11]),
        "=&v"(a[12]), "=&v"(a[13]), "=&v"(a[14]), "=&v"(a[15])
      : "v"(p)
      : "memory");
}

// 4 device-scope short stores (rows erow..erow+3, stride NH*2=1024B) + drain.
__device__ __forceinline__ void store_h4(unsigned short* p, unsigned v0,
                                         unsigned v1, unsigned v2, unsigned v3) {
  asm volatile(
      "global_store_short %0, %1, off sc1\n\t"
      "global_store_short %0, %2, off offset:1024 sc1\n\t"
      "global_store_short %0, %3, off offset:2048 sc1\n\t"
      "global_store_short %0, %4, off offset:3072 sc1\n\t"
      "s_waitcnt vmcnt(0)"
      :
      : "v"(p), "v"(v0), "v"(v1), "v"(v2), "v"(v3)
      : "memory");
}

__device__ __forceinline__ unsigned poll_load_dev(const unsigned* p) {
  unsigned f;
  asm volatile(
      "global_load_dword %0, %1, off sc1\n\t"
      "s_waitcnt vmcnt(0)"
      : "=v"(f) : "v"(p) : "memory");
  return f;
}

// system-scope poll: guaranteed fresh.
__device__ __forceinline__ unsigned poll_load_sys(const unsigned* p) {
  unsigned f;
  asm volatile(
      "global_load_dword %0, %1, off sc0 sc1\n\t"
      "s_waitcnt vmcnt(0)"
      : "=v"(f) : "v"(p) : "memory");
  return f;
}

__device__ __forceinline__ void flag_store(unsigned* p, unsigned v) {
  asm volatile("global_store_dword %0, %1, off sc1"
               :: "v"(p), "v"(v) : "memory");
}
__device__ __forceinline__ void flag_store_sys(unsigned* p, unsigned v) {
  asm volatile("global_store_dword %0, %1, off sc0 sc1"
               :: "v"(p), "v"(v) : "memory");
}
__device__ __forceinline__ void store_short_coh(unsigned short* p, unsigned v) {
  asm volatile("global_store_short %0, %1, off sc0 sc1"
               :: "v"(p), "v"(v) : "memory");
}

// ---------------------------------------------------------------------------
// Fused kernel. Blocks 0..63: recurrence (R14-exact). Blocks 64..255: IG
// producers. Tile T (0..6143): qt=T/1536, b=(T%1536)/12, bn=T%12,
// bm=b*4+qt -> output rows [bm*128,+128) of BT, cols [bn*128,+128) of 3H.
// igflags[bm*12+bn]=1 once the tile is drained.
// ---------------------------------------------------------------------------
template <bool USE_IG>
__global__ __launch_bounds__(256, 1) void gru_fused(
    const float* __restrict__ x, const float* __restrict__ Wih,
    const float* __restrict__ Whh, const float* __restrict__ bias,
    const float* __restrict__ bn, unsigned short* __restrict__ IG,
    unsigned short* __restrict__ hbuf, unsigned* __restrict__ hflags,
    unsigned* __restrict__ igflags, float* __restrict__ hfin) {
  __shared__ unsigned short As[128 * 40];
  __shared__ unsigned short Bs[128 * 40];

  const int tid = threadIdx.x;
  const int lane = tid & 63;
  const int w = tid >> 6;
  const int wm = w >> 1, wn = w & 1;
  const int l15 = lane & 15, q = lane >> 4;

  if (USE_IG && blockIdx.x >= 64) {
    // ---------------- producer path: 192 blocks, 32 tiles each -------------
    const int pid = blockIdx.x - 64;
    for (int T = pid; T < 6144; T += 192) {
      const int qt = T / 1536;
      const int rem = T - qt * 1536;
      const int b = rem / 12;
      const int bnn = rem - b * 12;
      const int bm = b * 4 + qt;

      f32x4 acc[4][4] = {};
      for (int kt = 0; kt < 16; ++kt) {
        __syncthreads();
#pragma unroll
        for (int j = 0; j < 4; ++j) {
          int fi = tid + 256 * j;
          int row = fi >> 3, kq = fi & 7;
          float4 v = *(const float4*)(x + (size_t)(bm * 128 + row) * ND + kt * 32 + kq * 4);
          ushort4 s = {f2bf(v.x), f2bf(v.y), f2bf(v.z), f2bf(v.w)};
          *(ushort4*)&As[row * 40 + kq * 4] = s;
        }
#pragma unroll
        for (int j = 0; j < 4; ++j) {
          int fi = tid + 256 * j;
          int row = fi >> 3, kq = fi & 7;
          float4 v = *(const float4*)(Wih + (size_t)(bnn * 128 + row) * ND + kt * 32 + kq * 4);
          ushort4 s = {f2bf(v.x), f2bf(v.y), f2bf(v.z), f2bf(v.w)};
          *(ushort4*)&Bs[row * 40 + kq * 4] = s;
        }
        __syncthreads();

        short8 af[4], bfv[4];
#pragma unroll
        for (int tm = 0; tm < 4; ++tm)
          af[tm] = *(const short8*)&As[(wm * 64 + tm * 16 + l15) * 40 + q * 8];
#pragma unroll
        for (int tn = 0; tn < 4; ++tn)
          bfv[tn] = *(const short8*)&Bs[(wn * 64 + tn * 16 + l15) * 40 + q * 8];
#pragma unroll
        for (int tm = 0; tm < 4; ++tm)
#pragma unroll
          for (int tn = 0; tn < 4; ++tn)
            acc[tm][tn] = __builtin_amdgcn_mfma_f32_16x16x32_bf16(af[tm], bfv[tn], acc[tm][tn], 0, 0, 0);
      }

      // epilogue: coherent stores -> drain -> tile flag
#pragma unroll
      for (int tm = 0; tm < 4; ++tm) {
#pragma unroll
        for (int tn = 0; tn < 4; ++tn) {
          int ccol = bnn * 128 + wn * 64 + tn * 16 + l15;
          float bb = bias[ccol];
#pragma unroll
          for (int i = 0; i < 4; ++i) {
            int row = bm * 128 + wm * 64 + tm * 16 + q * 4 + i;
            store_short_coh(IG + (size_t)row * NG + ccol,
                            (unsigned)f2bf(acc[tm][tn][i] + bb));
          }
        }
      }
      asm volatile("s_waitcnt vmcnt(0)" ::: "memory");
      __syncthreads();  // all waves drained before the flag goes out
      if (tid == 0) flag_store_sys(igflags + bm * 12 + bnn, 1u);
    }
    return;
  }
  if (!USE_IG && blockIdx.x >= 64) return;

  // ---------------- consumer path: R14-exact h ring + IG quarter gate -----
  const int g = blockIdx.x >> 4;   // 4 groups
  const int c = blockIdx.x & 15;   // 16 col-chunks of 32
  const int b0 = g * 32;
  const int col = c * 32 + wn * 16 + l15;  // this lane's h column
  const int mrow = b0 + wm * 16 + l15;     // A-fragment batch row
  const int erow = b0 + wm * 16 + q * 4;   // C-layout batch row base

  unsigned* const myflag = hflags + ((g * 2 + wm) * 16 + c) * 2 + wn;
  const unsigned* const pollbase = hflags + (g * 2 + wm) * 32;  // 32 flags

  // Whh B-fragments -> registers: 3 gates x 16 k-chunks (192 VGPRs)
  short8 bfr[3][16];
#pragma unroll
  for (int gt = 0; gt < 3; ++gt) {
    const float* src = Whh + (size_t)(gt * NH + col) * NH + q * 8;
#pragma unroll
    for (int kk = 0; kk < 16; ++kk) {
      float4 v0 = *(const float4*)(src + kk * 32);
      float4 v1 = *(const float4*)(src + kk * 32 + 4);
      bfr[gt][kk] = pack8(v0, v1);
    }
  }

  float bi_r = 0.f, bi_z = 0.f, bi_n = 0.f;
  if (!USE_IG) {
    bi_r = bias[col];
    bi_z = bias[NH + col];
    bi_n = bias[2 * NH + col];
  }
  const float bnv = bn[col];

  float hreg[4] = {0.f, 0.f, 0.f, 0.f};

  unsigned short* const hb0 = hbuf;
  unsigned short* const hb1 = hbuf + NB * NH;

  for (int t = 0; t < NT; ++t) {
    const unsigned short* hcur = (t & 1) ? hb1 : hb0;
    unsigned short* hnxt = (t & 1) ? hb0 : hb1;

    // IG quarter gate (4x per run): before ANY touch of this quarter's IG,
    // wait for the tiles covering this block's rows x 3 gate-columns.
    if (USE_IG && (t & 127) == 0) {
      const int qt = t >> 7;
      if (lane < 32) {
        const int bb = b0 + lane;
#pragma unroll
        for (int gi = 0; gi < 3; ++gi) {
          const unsigned* fp = igflags + (size_t)(bb * 4 + qt) * 12 + (c >> 2) + gi * 4;
          unsigned f = poll_load_sys(fp);
          while (f == 0u) f = poll_load_sys(fp);
        }
      }
      // implicit reconvergence before first IG load below
    }

    // IG loads (plain cached; first touch is after the quarter gate).
    float igr[4], igz[4], ign[4];
    if (USE_IG) {
#pragma unroll
      for (int i = 0; i < 4; ++i) {
        const size_t base = ((size_t)(erow + i) * NT + t) * NG + col;
        igr[i] = bf2f(IG[base]);
        igz[i] = bf2f(IG[base + NH]);
        ign[i] = bf2f(IG[base + 2 * NH]);
      }
    }

    int4v araw[16];
    if (t > 0) {
      // wait for the 32 producer waves of this row-half to have written h_t.
      if (lane < 32) {
        const unsigned* fp = pollbase + lane;
        unsigned f = poll_load_dev(fp);
        int tries = 0;
        while ((int)f < t) {
          if (++tries > 8) f = poll_load_sys(fp);
          else             f = poll_load_dev(fp);
        }
      }
      load_h16(hcur + (size_t)mrow * NH + q * 8, araw);
    } else {
#pragma unroll
      for (int kk = 0; kk < 16; ++kk) araw[kk] = (int4v){0, 0, 0, 0};
    }

    f32x4 ar = {0.f, 0.f, 0.f, 0.f};
    f32x4 az = {0.f, 0.f, 0.f, 0.f};
    f32x4 an = {0.f, 0.f, 0.f, 0.f};
    f32x4 ai = {0.f, 0.f, 0.f, 0.f};
#pragma unroll
    for (int kk = 0; kk < 16; ++kk) {
      short8 afk = __builtin_bit_cast(short8, araw[kk]);
      ar = __builtin_amdgcn_mfma_f32_16x16x32_bf16(afk, bfr[0][kk], ar, 0, 0, 0);
      az = __builtin_amdgcn_mfma_f32_16x16x32_bf16(afk, bfr[1][kk], az, 0, 0, 0);
      an = __builtin_amdgcn_mfma_f32_16x16x32_bf16(afk, bfr[2][kk], an, 0, 0, 0);
      if (!USE_IG) {
        const float* xp = x + ((size_t)mrow * NT + t) * ND + kk * 32 + q * 8;
        short8 xa = pack8(*(const float4*)xp, *(const float4*)(xp + 4));
#pragma unroll
        for (int gt = 0; gt < 3; ++gt) {
          const float* wp = Wih + (size_t)(gt * NH + col) * ND + kk * 32 + q * 8;
          short8 wf = pack8(*(const float4*)wp, *(const float4*)(wp + 4));
          if (gt == 0) ar = __builtin_amdgcn_mfma_f32_16x16x32_bf16(xa, wf, ar, 0, 0, 0);
          if (gt == 1) az = __builtin_amdgcn_mfma_f32_16x16x32_bf16(xa, wf, az, 0, 0, 0);
          if (gt == 2) ai = __builtin_amdgcn_mfma_f32_16x16x32_bf16(xa, wf, ai, 0, 0, 0);
        }
      }
    }

    // gates + h update; store, drain, flag (R4/R14 protocol)
    unsigned sv[4];
#pragma unroll
    for (int i = 0; i < 4; ++i) {
      float xr = USE_IG ? (ar[i] + igr[i]) : (ar[i] + bi_r);
      float xz = USE_IG ? (az[i] + igz[i]) : (az[i] + bi_z);
      float xin = USE_IG ? ign[i] : (ai[i] + bi_n);
      float r = sigmoid_f(xr);
      float z = sigmoid_f(xz);
      float n = tanh_f(xin + r * (an[i] + bnv));
      float hn2 = (1.f - z) * n + z * hreg[i];
      hreg[i] = hn2;
      sv[i] = (unsigned)f2bf(hn2);
      if (t == NT - 1) hfin[(size_t)(erow + i) * NH + col] = hn2;
    }
    if (t != NT - 1) {
      store_h4(hnxt + (size_t)erow * NH + col, sv[0], sv[1], sv[2], sv[3]);
      if (lane == 0) flag_store(myflag, (unsigned)(t + 1));
    }
  }
}

// ---------------------------------------------------------------------------
// out = h_T @ Wlin^T + blin; mu = cols [0,256), logvar = cols [256,512).
// ---------------------------------------------------------------------------
__global__ __launch_bounds__(256) void final_linear(
    const float* __restrict__ hfin, const float* __restrict__ Wlin,
    const float* __restrict__ blin, float* __restrict__ out) {
  __shared__ float sh[16 * 516];
  const int tid = threadIdx.x;
  const int b0 = blockIdx.y * 16, o0 = blockIdx.x * 16;

  for (int j = tid; j < 16 * 128; j += 256) {
    int row = j >> 7, kq = j & 127;
    *(float4*)&sh[row * 516 + kq * 4] =
        *(const float4*)(hfin + (size_t)(b0 + row) * NH + kq * 4);
  }
  __syncthreads();

  const int bi = tid & 15, oi = tid >> 4;
  const int o = o0 + oi;
  const float4* wp = (const float4*)(Wlin + (size_t)o * NH);
  float4 a4 = {0.f, 0.f, 0.f, 0.f};
  for (int k4 = 0; k4 < 128; ++k4) {
    float4 wv = wp[k4];
    float4 hv = *(const float4*)&sh[bi * 516 + k4 * 4];
    a4.x += wv.x * hv.x; a4.y += wv.y * hv.y;
    a4.z += wv.z * hv.z; a4.w += wv.w * hv.w;
  }
  float v = a4.x + a4.y + a4.z + a4.w + blin[o];
  int b = b0 + bi;
  if (o < 256) out[b * 256 + o] = v;
  else out[32768 + b * 256 + (o - 256)] = v;
}

// ---------------------------------------------------------------------------
extern "C" void kernel_launch(void* const* d_in, const int* in_sizes, int n_in,
                              void* d_out, int out_size, void* d_ws, size_t ws_size,
                              hipStream_t stream) {
  const float* x    = (const float*)d_in[0];
  const float* Wih  = (const float*)d_in[1];
  const float* Whh  = (const float*)d_in[2];
  const float* bias = (const float*)d_in[3];
  const float* bn   = (const float*)d_in[4];
  const float* Wlin = (const float*)d_in[5];
  const float* blin = (const float*)d_in[6];
  float* out = (float*)d_out;

  char* ws = (char*)d_ws;
  // layout: [hbuf 262144][hflags 1024][igflags 24576][hfin 262144][IG ...]
  unsigned short* hbuf = (unsigned short*)ws;
  unsigned* hflags     = (unsigned*)(ws + 262144);
  unsigned* igflags    = (unsigned*)(ws + 263168);
  float* hfin          = (float*)(ws + 287744);
  unsigned short* IG   = (unsigned short*)(ws + 549888);
  const size_t need_min = 549888;
  const size_t need_ig  = 549888 + (size_t)NB * NT * NG * 2;  // ~203 MB
  if (ws_size < need_min) return;

  // zero hflags + igflags (flag 0 < any live value)
  hipMemsetAsync(ws + 262144, 0, 1024 + 24576, stream);

  const bool useIG = (ws_size >= need_ig);
  if (useIG) {
    gru_fused<true><<<256, 256, 0, stream>>>(x, Wih, Whh, bias, bn, IG,
                                             hbuf, hflags, igflags, hfin);
  } else {
    gru_fused<false><<<64, 256, 0, stream>>>(x, Wih, Whh, bias, bn, nullptr,
                                             hbuf, hflags, igflags, hfin);
  }
  final_linear<<<dim3(32, 8), 256, 0, stream>>>(hfin, Wlin, blin, out);
}